// Round 13
// baseline (142.051 us; speedup 1.0000x reference)
//
#include <hip/hip_runtime.h>
#include <hip/hip_bf16.h>

// Problem constants (B=1, N=2048, D=1024, H=16, HD=64; NO=74 offsets)
#define SEQ_N 2048
#define DIM   1024
#define NHEAD 16
#define HDIM  64
#define LDQ   4096   // qkvg row stride: [q | k | v | gatepre]
#define NOFF  74     // 65 dense (0..64) + 9 dyadic
#define NDENSE 65
#define NJ    224    // 80 dense rows + 9*16 dyadic rows
#define NT    16     // n-rows per attention block
#define PST   232    // Pd row stride (padded, 16B-aligned)
#define QST   88     // Qbuf row stride (16B-aligned)

typedef __attribute__((ext_vector_type(8)))  __bf16 bv8;
typedef __attribute__((ext_vector_type(4)))  __bf16 bv4;
typedef __attribute__((ext_vector_type(4)))  float  f32x4;
typedef __attribute__((ext_vector_type(16))) float  f32x16;

typedef __attribute__((address_space(3))) void as3_void;
typedef __attribute__((address_space(1))) void as1_void;

// async global->LDS 16B copy. LDS dest must be wave-uniform base + lane*16.
__device__ __forceinline__ void async16(const void* g, void* l) {
  __builtin_amdgcn_global_load_lds((as1_void*)(unsigned long long)g,
                                   (as3_void*)l, 16, 0, 0);
}

// XCD 2D-tiled block mapping for 512-block grids. Heuristic: consecutive
// dispatch IDs round-robin the 8 XCDs (f&7). Give each XCD an 8x8 block
// region so its L2 working set is (8*TM rows of A) + (8*TN rows of B)
// ~= 4 MB = one XCD's L2. GX = regions along x (GX * (8/GX) layout).
__device__ __forceinline__ void xcd_map(int GX, int& bx, int& by) {
  int f = blockIdx.y * gridDim.x + blockIdx.x;
  int xcd = f & 7, i = f >> 3;
  bx = (xcd % GX) * 8 + (i & 7);
  by = (xcd / GX) * 8 + (i >> 3);
}

// ---------------------------------------------------------------------------
// fp32 -> bf16 convert, all 4 tensors in one launch (dst regions contiguous).
// ---------------------------------------------------------------------------
#define E1 (SEQ_N * DIM)            // x
#define E2 (E1 + 3 * DIM * DIM)     // + Wqkv
#define E3 (E2 + DIM * DIM)         // + Wgate
#define E4 (E3 + DIM * DIM)         // + Wout
__global__ __launch_bounds__(256) void cvt_all(
    const float* __restrict__ x, const float* __restrict__ wqkv,
    const float* __restrict__ wgate, const float* __restrict__ wout,
    __bf16* __restrict__ dst) {
  long i = ((long)blockIdx.x * 256 + threadIdx.x) * 4;
  if (i >= E4) return;
  const float* s; long o;
  if (i < E1)      { s = x;     o = i; }
  else if (i < E2) { s = wqkv;  o = i - E1; }
  else if (i < E3) { s = wgate; o = i - E2; }
  else             { s = wout;  o = i - E3; }
  float4 v = *(const float4*)(s + o);
  bv4 ov;
  ov[0] = (__bf16)v.x; ov[1] = (__bf16)v.y; ov[2] = (__bf16)v.z; ov[3] = (__bf16)v.w;
  *(bv4*)(dst + i) = ov;
}

// ---------------------------------------------------------------------------
// GEMM (128xBN_ tile, BKT=128): C = A[MxK] * B[NoutxK]^T + bias, bf16 in,
// fp32 accum, OutT out. B split at col Nsplit. m97 staging (async16 w=16),
// global-side XOR chunk-swizzle (R9), 32x32x16 MFMA (R12, neutral-kept).
// R13: XCD 2D-tiled block mapping (8x8 regions -> 4 MB L2 working set/XCD).
// Grid must be 32x16 (gemm1).
// ---------------------------------------------------------------------------
#define BM 128
#define BKT 128

template <int BN_, typename OutT>
__global__ __launch_bounds__(256) void gemm_bt(
    const __bf16* __restrict__ A, const __bf16* __restrict__ B1,
    const __bf16* __restrict__ B2, const float* __restrict__ bias1,
    const float* __restrict__ bias2, int Nsplit,
    OutT* __restrict__ C, int ldc, int K) {
  __shared__ __attribute__((aligned(16))) __bf16 Asm[BM * BKT];   // 32 KB
  __shared__ __attribute__((aligned(16))) __bf16 Bsm[BN_ * BKT];  // 32 KB
  constexpr int NJ32 = BN_ / 64;           // 32-col j-tiles per wave
  constexpr int CA = BM * BKT / 8;
  constexpr int CB = BN_ * BKT / 8;
  constexpr int CPR = BKT / 8;             // 16

  const int tid  = threadIdx.x;
  const int lane = tid & 63;
  const int wave = tid >> 6;
  const int wr = wave >> 1, wc = wave & 1;
  const int m31 = lane & 31;               // MFMA row/col within 32-tile
  const int h1  = lane >> 5;               // k-half selector
  const int l7  = lane & 7;                // swizzle key (= row&7)

  int bxi, byi;
  xcd_map(4, bxi, byi);                    // grid 32x16: 4x2 regions of 8x8
  const int bn0 = bxi * BN_;
  const int bm0 = byi * BM;

  const __bf16* Bp;
  const float* biasp;
  if (bn0 < Nsplit) { Bp = B1 + (size_t)bn0 * K;            biasp = bias1 + bn0; }
  else              { Bp = B2 + (size_t)(bn0 - Nsplit) * K; biasp = bias2 + (bn0 - Nsplit); }
  const __bf16* Ap = A + (size_t)bm0 * K;

  f32x16 acc[2][NJ32] = {};

  for (int kt = 0; kt < K; kt += BKT) {
    __syncthreads();
#pragma unroll
    for (int c0 = 0; c0 < CA + CB; c0 += 256) {
      int c = c0 + tid;
      if (c < CA) {
        int rr = c / CPR, qq = c % CPR;
        int qs = qq ^ (rr & 7);
        async16(Ap + (size_t)rr * K + kt + qs * 8, Asm + c * 8);
      } else {
        int cb = c - CA;
        int rr = cb / CPR, qq = cb % CPR;
        int qs = qq ^ (rr & 7);
        async16(Bp + (size_t)rr * K + kt + qs * 8, Bsm + cb * 8);
      }
    }
    __syncthreads();

#pragma unroll
    for (int kk = 0; kk < BKT / 16; ++kk) {
      const int qs = ((kk * 2 + h1) ^ l7) * 8;
      bv8 af[2], bfr[NJ32];
#pragma unroll
      for (int i = 0; i < 2; ++i)
        af[i] = *(const bv8*)(Asm + (wr * 64 + i * 32 + m31) * BKT + qs);
#pragma unroll
      for (int j = 0; j < NJ32; ++j)
        bfr[j] = *(const bv8*)(Bsm + (wc * (BN_ / 2) + j * 32 + m31) * BKT + qs);
#pragma unroll
      for (int i = 0; i < 2; ++i)
#pragma unroll
        for (int j = 0; j < NJ32; ++j)
          acc[i][j] = __builtin_amdgcn_mfma_f32_32x32x16_bf16(af[i], bfr[j], acc[i][j], 0, 0, 0);
    }
  }

#pragma unroll
  for (int i = 0; i < 2; ++i) {
#pragma unroll
    for (int j = 0; j < NJ32; ++j) {
      int ccol = wc * (BN_ / 2) + j * 32 + m31;
      float b = biasp[ccol];
#pragma unroll
      for (int reg = 0; reg < 16; ++reg) {
        int row = bm0 + wr * 64 + i * 32 + (reg & 3) + 8 * (reg >> 2) + 4 * h1;
        C[(size_t)row * ldc + bn0 + ccol] = (OutT)(acc[i][j][reg] + b);
      }
    }
  }
}

// ---------------------------------------------------------------------------
// GEMM 64x64 tile, BKT=128 (gemm3). 32x32x16 MFMA + XOR chunk-swizzle.
// R13: XCD 2D-tiled mapping. Grid must be 16x32.
// ---------------------------------------------------------------------------
template <typename OutT>
__global__ __launch_bounds__(256) void gemm_bt64(
    const __bf16* __restrict__ A, const __bf16* __restrict__ B,
    const float* __restrict__ bias, OutT* __restrict__ C, int ldc, int K) {
  __shared__ __attribute__((aligned(16))) __bf16 Asm[64 * BKT];  // 16 KB
  __shared__ __attribute__((aligned(16))) __bf16 Bsm[64 * BKT];  // 16 KB
  constexpr int CM = 64 * BKT / 8;         // 1024 chunks per matrix
  constexpr int CPR = BKT / 8;             // 16

  const int tid  = threadIdx.x;
  const int lane = tid & 63;
  const int wave = tid >> 6;
  const int wr = wave >> 1, wc = wave & 1;
  const int m31 = lane & 31;
  const int h1  = lane >> 5;
  const int l7  = lane & 7;

  int bxi, byi;
  xcd_map(2, bxi, byi);                    // grid 16x32: 2x4 regions of 8x8
  const int bn0 = bxi * 64;
  const int bm0 = byi * 64;

  const __bf16* Ap = A + (size_t)bm0 * K;
  const __bf16* Bp = B + (size_t)bn0 * K;
  const float* biasp = bias + bn0;

  f32x16 acc = {};

  for (int kt = 0; kt < K; kt += BKT) {
    __syncthreads();
#pragma unroll
    for (int c0 = 0; c0 < CM; c0 += 256) {
      int c = c0 + tid;
      int rr = c / CPR, qq = c % CPR;
      int qs = qq ^ (rr & 7);
      async16(Ap + (size_t)rr * K + kt + qs * 8, Asm + c * 8);
      async16(Bp + (size_t)rr * K + kt + qs * 8, Bsm + c * 8);
    }
    __syncthreads();

#pragma unroll
    for (int kk = 0; kk < BKT / 16; ++kk) {
      const int qs = ((kk * 2 + h1) ^ l7) * 8;
      bv8 a = *(const bv8*)(Asm + (wr * 32 + m31) * BKT + qs);
      bv8 b = *(const bv8*)(Bsm + (wc * 32 + m31) * BKT + qs);
      acc = __builtin_amdgcn_mfma_f32_32x32x16_bf16(a, b, acc, 0, 0, 0);
    }
  }

  {
    int ccol = wc * 32 + m31;
    float b = biasp[ccol];
#pragma unroll
    for (int reg = 0; reg < 16; ++reg) {
      int row = bm0 + wr * 32 + (reg & 3) + 8 * (reg >> 2) + 4 * h1;
      C[(size_t)row * ldc + bn0 + ccol] = (OutT)(acc[reg] + b);
    }
  }
}

// ---------------------------------------------------------------------------
// MFMA-tile attention + gate (R11 version: single K/V buffer, V staged
// during softmax; 44.1 KB LDS -> 3 blocks/CU). Unchanged this round.
// ---------------------------------------------------------------------------
__global__ __launch_bounds__(256) void attn_mfma(
    const __bf16* __restrict__ qkv,      // [SEQ_N x LDQ]
    const float* __restrict__ pos_bias,  // [NOFF x NHEAD]
    const int* __restrict__ offsets,     // [NOFF]
    __bf16* __restrict__ fg) {
  const int n0 = (blockIdx.x >> 4) * NT;
  const int h  = blockIdx.x & 15;
  const int tid = threadIdx.x;
  const int lane = tid & 63;
  const int w = tid >> 6;
  const int fr = lane & 15, fq = lane >> 4;
  const int fr7 = fr & 7;

  __shared__ __attribute__((aligned(16))) __bf16 KVbuf[NJ * HDIM];  // 28672 B
  __shared__ __attribute__((aligned(16))) __bf16 Qbuf[NT * QST];    // 2816 B
  __shared__ __attribute__((aligned(16))) float  Sbuf[NT][80];      // 5120 B
  __shared__ __attribute__((aligned(16))) __bf16 Pd[NT * PST];      // 7424 B
  __shared__ float inv_l[NT];

  const int ch = lane & 7;
  const int rowin = lane >> 3;          // 0..7, equals (row index)&7

  // --- Phase 0: stage Q, zero Pd, async-stage K (swizzled chunks) ---
  if (tid < 128) {
    int ni = tid >> 3, cq = tid & 7;
    bv8 q = *(const bv8*)(qkv + (size_t)(n0 + ni) * LDQ + h * HDIM + cq * 8);
    *(bv8*)(Qbuf + ni * QST + cq * 8) = q;
  }
#pragma unroll
  for (int c0 = 0; c0 < NT * PST / 8; c0 += 256) {
    int c = c0 + tid;
    if (c < NT * PST / 8) *(uint4*)(Pd + c * 8) = make_uint4(0, 0, 0, 0);
  }
  {
    int chs = ch ^ rowin;           // swizzled k-chunk for K staging
#pragma unroll
    for (int it = 0; it < 7; ++it) {
      int jbase = it * 32 + w * 8;
      int j = jbase + rowin;
      int g;
      if (j < 80) g = n0 - 64 + j;
      else { int jj = j - 80; g = n0 - offsets[NDENSE + (jj >> 4)] + (jj & 15); }
      if (g < 0) g = 0;   // clamp; masked later
      async16(qkv + (size_t)g * LDQ + DIM + h * HDIM + chs * 8,
              KVbuf + jbase * HDIM + lane * 8);
    }
  }
  __syncthreads();

  // --- Phase 1: scores via MFMA, scatter banded entries to Sbuf ---
  for (int jb = w; jb < 14; jb += 4) {
    f32x4 acc = {};
#pragma unroll
    for (int kk = 0; kk < 2; ++kk) {
      bv8 a = *(const bv8*)(Qbuf + fr * QST + kk * 32 + fq * 8);
      bv8 b = *(const bv8*)(KVbuf + (jb * 16 + fr) * HDIM + ((kk * 4 + fq) ^ fr7) * 8);
      acc = __builtin_amdgcn_mfma_f32_16x16x32_bf16(a, b, acc, 0, 0, 0);
    }
    int j = jb * 16 + fr;           // K row this lane's column maps to
    if (jb < 5) {                   // dense region
      bool gvalid = (n0 - 64 + j) >= 0;
#pragma unroll
      for (int r = 0; r < 4; ++r) {
        int ni = fq * 4 + r;
        int o = ni + 64 - j;
        if (o >= 0 && o < NDENSE)
          Sbuf[ni][o] = gvalid ? acc[r] : -3.0e38f;
      }
    } else {                        // dyadic: only diagonal entries used
      int jj = j - 80;
      int s = jj >> 4, tni = jj & 15;
      int r = tni - fq * 4;
      if (r >= 0 && r < 4) {
        bool gvalid = (n0 + tni - offsets[NDENSE + s]) >= 0;
        Sbuf[tni][NDENSE + s] = gvalid ? acc[r] : -3.0e38f;
      }
    }
  }
  __syncthreads();   // all K reads done -> KVbuf reusable; Sbuf published

  // --- stage V into KVbuf (plain chunks); overlaps Phase-2 softmax ---
#pragma unroll
  for (int it = 0; it < 7; ++it) {
    int jbase = it * 32 + w * 8;
    int j = jbase + rowin;
    int g;
    if (j < 80) g = n0 - 64 + j;
    else { int jj = j - 80; g = n0 - offsets[NDENSE + (jj >> 4)] + (jj & 15); }
    if (g < 0) g = 0;
    async16(qkv + (size_t)g * LDQ + 2 * DIM + h * HDIM + ch * 8,
            KVbuf + jbase * HDIM + lane * 8);
  }

  // --- Phase 2: softmax (16 threads per row), banded P -> Pd (bf16) ---
  {
    int t = tid & 15, ni = tid >> 4;
    float sc5[5];
    float m = -3.0e38f;
#pragma unroll
    for (int k = 0; k < 5; ++k) {
      int o = t + k * 16;
      float v = -3.0e38f;
      if (o < NOFF) {
        float raw = Sbuf[ni][o];
        if (raw > -1.0e38f) v = raw * 0.125f + pos_bias[o * NHEAD + h];
      }
      sc5[k] = v;
      m = fmaxf(m, v);
    }
#pragma unroll
    for (int d = 1; d < 16; d <<= 1) m = fmaxf(m, __shfl_xor(m, d));
    float sum = 0.f;
#pragma unroll
    for (int k = 0; k < 5; ++k) {
      int o = t + k * 16;
      if (o < NOFF && sc5[k] > -1.0e38f) {
        float e = __expf(sc5[k] - m);
        sum += e;
        int j = (o < NDENSE) ? (ni + 64 - o) : (80 + (o - NDENSE) * 16 + ni);
        Pd[ni * PST + j] = (__bf16)e;
      }
    }
#pragma unroll
    for (int d = 1; d < 16; d <<= 1) sum += __shfl_xor(sum, d);
    if (t == 0) inv_l[ni] = 1.f / sum;
  }
  __syncthreads();   // drains V async16s (vmcnt 0) + publishes Pd/inv_l

  // --- Phase 3: PV via MFMA (each wave one 16-col d-tile) + gate epilogue ---
  {
    const int db = w;
    f32x4 acc = {};
#pragma unroll
    for (int kt = 0; kt < 7; ++kt) {
      bv8 a = *(const bv8*)(Pd + fr * PST + kt * 32 + fq * 8);
      bv8 b;
#pragma unroll
      for (int jj = 0; jj < 8; ++jj)
        b[jj] = KVbuf[(kt * 32 + fq * 8 + jj) * HDIM + db * 16 + fr];
      acc = __builtin_amdgcn_mfma_f32_16x16x32_bf16(a, b, acc, 0, 0, 0);
    }
    int d = db * 16 + fr;
#pragma unroll
    for (int r = 0; r < 4; ++r) {
      int ni = fq * 4 + r;
      float o = acc[r] * inv_l[ni];
      float gp = (float)qkv[(size_t)(n0 + ni) * LDQ + 3 * DIM + h * HDIM + d];
      float gate = 1.f / (1.f + __expf(-gp));
      fg[(size_t)(n0 + ni) * DIM + h * HDIM + d] = (__bf16)(o * gate);
    }
  }
}

// ---------------------------------------------------------------------------
extern "C" void kernel_launch(void* const* d_in, const int* in_sizes, int n_in,
                              void* d_out, int out_size, void* d_ws, size_t ws_size,
                              hipStream_t stream) {
  const float* x        = (const float*)d_in[0];
  const float* Wqkv     = (const float*)d_in[1];
  const float* bqkv     = (const float*)d_in[2];
  const float* Wgate    = (const float*)d_in[3];
  const float* bgate    = (const float*)d_in[4];
  const float* Wout     = (const float*)d_in[5];
  const float* bout     = (const float*)d_in[6];
  const float* pos_bias = (const float*)d_in[7];
  const int*   offsets  = (const int*)d_in[8];
  float* out = (float*)d_out;

  // workspace layout (bf16), cvt dst regions contiguous in this order
  __bf16* xb       = (__bf16*)d_ws;                               // 2048x1024
  __bf16* Wqkvb    = xb    + (size_t)SEQ_N * DIM;                 // 3072x1024
  __bf16* Wgateb   = Wqkvb + (size_t)3 * DIM * DIM;               // 1024x1024
  __bf16* Woutb    = Wgateb + (size_t)DIM * DIM;                  // 1024x1024
  __bf16* qkvg     = Woutb + (size_t)DIM * DIM;                   // 2048x4096
  __bf16* flatgate = qkvg + (size_t)SEQ_N * LDQ;                  // 2048x1024

  // 0) fp32 -> bf16 (single launch)
  cvt_all<<<dim3(E4 / 1024), dim3(256), 0, stream>>>(x, Wqkv, Wgate, Wout, xb);

  // 1) [qkv | gate_pre] = x @ [Wqkv;Wgate]^T + [bqkv;bgate]  -> bf16 qkvg
  gemm_bt<128, __bf16><<<dim3(LDQ / 128, SEQ_N / BM), dim3(256), 0, stream>>>(
      xb, Wqkvb, Wgateb, bqkv, bgate, 3 * DIM, qkvg, LDQ, DIM);

  // 2) attention + sigmoid-gate fuse -> flatgate (bf16)
  attn_mfma<<<dim3((SEQ_N / NT) * NHEAD), dim3(256), 0, stream>>>(
      qkvg, pos_bias, offsets, flatgate);

  // 3) out = flatgate @ Wout^T + bout  -> fp32 d_out (64x64 tiles: 512 blocks)
  gemm_bt64<float><<<dim3(DIM / 64, SEQ_N / 64), dim3(256), 0, stream>>>(
      flatgate, Woutb, bout, out, DIM, DIM);
}